// Round 12
// baseline (32.016 us; speedup 1.0000x reference)
//
#include <hip/hip_runtime.h>

// Direct-Form-II biquad over [B=64][T=262144]; fully independent blocks via
// warm-up truncation; TWO consecutive tiles per block (B continues A exactly,
// no second warm-up).  v[t+1] = A v[t] + c x[t],  A = [[-a1,1],[-a2,0]],
// c = [b1-a1*b0, b2-a2*b0],  out[t] = b0 x[t] + v0[t].
// Block g: batch b=g>>4, pos k=g&15, samples [k*16384, +16384). Tile-A start
// from 4096 preceding samples, zero-init (stable filter, err ~ rho^4096).
// One triple scan (W@A^16, A,B@A^32), shared ladders, 3 barriers, no atomics.

constexpr int BATCH = 64;
constexpr int T_LEN = 262144;
constexpr int TPB   = 256;            // threads per block
constexpr int LPT   = 32;             // samples per thread per tile
constexpr int TILE  = TPB * LPT;      // 8192 samples per tile
constexpr int SPAN  = 2 * TILE;       // 16384 samples per block
constexpr int NBPB  = T_LEN / SPAN;   // 16 blocks per batch chain
constexpr int NB    = BATCH * NBPB;   // 1024 blocks
constexpr int WUP   = 4096;           // warm-up samples (tile A only)

typedef float vfloat4 __attribute__((ext_vector_type(4)));

#define MATSQ(m00, m01, m10, m11)                                  \
    {                                                              \
        float n00 = fmaf(m00, m00, m01 * m10);                     \
        float n01 = fmaf(m00, m01, m01 * m11);                     \
        float n10 = fmaf(m10, m00, m11 * m10);                     \
        float n11 = fmaf(m10, m01, m11 * m11);                     \
        m00 = n00; m01 = n01; m10 = n10; m11 = n11;                \
    }

// composed 4-step update: v <- A^4 v + k3*xa + k2*xb + k1*xc + c*xd
#define CSTEP(p0, p1, xa, xb, xc, xd)                                        \
    {                                                                        \
        float n0 = fmaf(q00, p0, fmaf(q01, p1,                               \
                   fmaf(k3_0, (xa), fmaf(k2_0, (xb),                         \
                   fmaf(k1_0, (xc), c0 * (xd))))));                          \
        float n1 = fmaf(q10, p0, fmaf(q11, p1,                               \
                   fmaf(k3_1, (xa), fmaf(k2_1, (xb),                         \
                   fmaf(k1_1, (xc), c1 * (xd))))));                          \
        p0 = n0; p1 = n1;                                                    \
    }

__global__ __launch_bounds__(TPB, 2) void biquad_2tile(
    const float* __restrict__ x, float* __restrict__ out,
    const float* __restrict__ pb0, const float* __restrict__ pb1,
    const float* __restrict__ pb2, const float* __restrict__ pa1,
    const float* __restrict__ pa2)
{
    __shared__ float ldsA[TPB][LPT + 1];   // 33,792 B
    __shared__ float ldsB[TPB][LPT + 1];   // 33,792 B
    __shared__ float swv[24];              // per wave w: [6w+0,1]=W [2,3]=A [4,5]=B

    const int tid  = threadIdx.x;
    const int lane = tid & 63;
    const int w    = tid >> 6;
    const int g    = blockIdx.x;
    const int b    = g >> 4;
    const int k    = g & (NBPB - 1);

    const float b0 = *pb0, b1 = *pb1, b2 = *pb2;
    const float a1 = *pa1, a2 = *pa2;
    const float na1 = -a1, na2 = -a2;

    // composed constants: c, k1=Ac, k2=A^2c, k3=A^3c, q=A^4
    const float c0 = fmaf(na1, b0, b1), c1 = fmaf(na2, b0, b2);
    const float A00 = na1, A01 = 1.f, A10 = na2, A11 = 0.f;
    const float k1_0 = fmaf(A00, c0, A01 * c1);
    const float k1_1 = fmaf(A10, c0, A11 * c1);
    float B00 = A00, B01 = A01, B10 = A10, B11 = A11;
    MATSQ(B00, B01, B10, B11);                           // A^2
    const float k2_0 = fmaf(B00, c0, B01 * c1);
    const float k2_1 = fmaf(B10, c0, B11 * c1);
    const float k3_0 = fmaf(B00, k1_0, B01 * k1_1);
    const float k3_1 = fmaf(B10, k1_0, B11 * k1_1);
    float q00 = B00, q01 = B01, q10 = B10, q11 = B11;
    MATSQ(q00, q01, q10, q11);                           // A^4

    const size_t base = (size_t)b * T_LEN + (size_t)k * SPAN;

    // ---- issue ALL global loads up front ----
    float4 wq[4];
    if (k > 0) {
        const float4* wsrc = reinterpret_cast<const float4*>(x + base - WUP) + tid * 4;
#pragma unroll
        for (int i = 0; i < 4; ++i) wq[i] = wsrc[i];
    }
    const float4* srcA = reinterpret_cast<const float4*>(x + base);
    const float4* srcB = srcA + TILE / 4;

    // stage tile A and tile B (coalesced loads, transposed LDS writes)
#pragma unroll
    for (int it = 0; it < 8; ++it) {
        int idx = it * TPB + tid;
        float4 v = srcA[idx];
        int e = idx * 4, c = e >> 5, t = e & 31;
        ldsA[c][t] = v.x; ldsA[c][t + 1] = v.y;
        ldsA[c][t + 2] = v.z; ldsA[c][t + 3] = v.w;
    }
#pragma unroll
    for (int it = 0; it < 8; ++it) {
        int idx = it * TPB + tid;
        float4 v = srcB[idx];
        int e = idx * 4, c = e >> 5, t = e & 31;
        ldsB[c][t] = v.x; ldsB[c][t + 1] = v.y;
        ldsB[c][t + 2] = v.z; ldsB[c][t + 3] = v.w;
    }
    __syncthreads();                                     // barrier #1

    // ---- pass 1: W (warm-up, A^16), A (A^32, regs), B (A^32, LDS rows) ----
    float xv[LPT];
#pragma unroll
    for (int t = 0; t < LPT; ++t) xv[t] = ldsA[tid][t];

    float pW0 = 0.f, pW1 = 0.f;
    if (k > 0) {
#pragma unroll
        for (int i = 0; i < 4; ++i)
            CSTEP(pW0, pW1, wq[i].x, wq[i].y, wq[i].z, wq[i].w);
    }
    float pA0 = 0.f, pA1 = 0.f;
#pragma unroll
    for (int i = 0; i < LPT / 4; ++i)
        CSTEP(pA0, pA1, xv[4 * i], xv[4 * i + 1], xv[4 * i + 2], xv[4 * i + 3]);
    float pB0 = 0.f, pB1 = 0.f;
#pragma unroll
    for (int i = 0; i < LPT / 4; ++i)
        CSTEP(pB0, pB1, ldsB[tid][4 * i], ldsB[tid][4 * i + 1],
                        ldsB[tid][4 * i + 2], ldsB[tid][4 * i + 3]);

    // chunk matrices: MW = A^16, M = A^32
    float wW00 = q00, wW01 = q01, wW10 = q10, wW11 = q11;
    MATSQ(wW00, wW01, wW10, wW11);                       // A^8
    MATSQ(wW00, wW01, wW10, wW11);                       // A^16
    float m00 = wW00, m01 = wW01, m10 = wW10, m11 = wW11;
    MATSQ(m00, m01, m10, m11);                           // A^32
    float wM00 = m00, wM01 = m01, wM10 = m10, wM11 = m11;

    // ---- triple in-wave inclusive scan (shfl only) ----
    for (int d = 1; d < 64; d <<= 1) {
        float oW0 = __shfl_up(pW0, d), oW1 = __shfl_up(pW1, d);
        float oA0 = __shfl_up(pA0, d), oA1 = __shfl_up(pA1, d);
        float oB0 = __shfl_up(pB0, d), oB1 = __shfl_up(pB1, d);
        if (lane >= d) {
            pW0 = fmaf(wW00, oW0, fmaf(wW01, oW1, pW0));
            pW1 = fmaf(wW10, oW0, fmaf(wW11, oW1, pW1));
            pA0 = fmaf(wM00, oA0, fmaf(wM01, oA1, pA0));
            pA1 = fmaf(wM10, oA0, fmaf(wM11, oA1, pA1));
            pB0 = fmaf(wM00, oB0, fmaf(wM01, oB1, pB0));
            pB1 = fmaf(wM10, oB0, fmaf(wM11, oB1, pB1));
        }
        MATSQ(wW00, wW01, wW10, wW11);
        MATSQ(wM00, wM01, wM10, wM11);
    }
    // post-scan: wW = A^1024 (QW), wM = A^2048 (QM)

    float einA0 = __shfl_up(pA0, 1), einA1 = __shfl_up(pA1, 1);
    float einB0 = __shfl_up(pB0, 1), einB1 = __shfl_up(pB1, 1);
    if (lane == 0) { einA0 = einA1 = einB0 = einB1 = 0.f; }

    if (lane == 63) {
        swv[6 * w]     = pW0; swv[6 * w + 1] = pW1;
        swv[6 * w + 2] = pA0; swv[6 * w + 3] = pA1;
        swv[6 * w + 4] = pB0; swv[6 * w + 5] = pB1;
    }
    __syncthreads();                                     // barrier #2

    // ---- Horner compositions over wave aggregates ----
    // sA = warm-up total (tile-A start state)
    float sA0 = 0.f, sA1 = 0.f;
#pragma unroll
    for (int u = 0; u < 4; ++u) {
        float t0 = fmaf(wW00, sA0, fmaf(wW01, sA1, swv[6 * u]));
        float t1 = fmaf(wW10, sA0, fmaf(wW11, sA1, swv[6 * u + 1]));
        sA0 = t0; sA1 = t1;
    }
    // aggA = tile-A total (zero-init); cwA/cwB = cross-wave exclusive prefixes
    float agA0 = 0.f, agA1 = 0.f;
#pragma unroll
    for (int u = 0; u < 4; ++u) {
        float t0 = fmaf(wM00, agA0, fmaf(wM01, agA1, swv[6 * u + 2]));
        float t1 = fmaf(wM10, agA0, fmaf(wM11, agA1, swv[6 * u + 3]));
        agA0 = t0; agA1 = t1;
    }
    float cwA0 = 0.f, cwA1 = 0.f, cwB0 = 0.f, cwB1 = 0.f;
    for (int u = 0; u < w; ++u) {                         // <=3 iters
        float t0 = fmaf(wM00, cwA0, fmaf(wM01, cwA1, swv[6 * u + 2]));
        float t1 = fmaf(wM10, cwA0, fmaf(wM11, cwA1, swv[6 * u + 3]));
        cwA0 = t0; cwA1 = t1;
        float u0 = fmaf(wM00, cwB0, fmaf(wM01, cwB1, swv[6 * u + 4]));
        float u1 = fmaf(wM10, cwB0, fmaf(wM11, cwB1, swv[6 * u + 5]));
        cwB0 = u0; cwB1 = u1;
    }
    // s_endA = A^8192 * sA + aggA   (tile-B start state); A^8192 = QM^4
    float P00 = wM00, P01 = wM01, P10 = wM10, P11 = wM11;
    MATSQ(P00, P01, P10, P11);
    MATSQ(P00, P01, P10, P11);                           // A^8192
    float sB0 = fmaf(P00, sA0, fmaf(P01, sA1, agA0));
    float sB1 = fmaf(P10, sA0, fmaf(P11, sA1, agA1));

    // ---- shared ladder (M = A^32): vX = M^tid*sX,  vcX = M^lane*cwX ----
    float vA0 = sA0, vA1 = sA1, vB0 = sB0, vB1 = sB1;
    float vcA0 = cwA0, vcA1 = cwA1, vcB0 = cwB0, vcB1 = cwB1;
    {
        float t00 = m00, t01 = m01, t10 = m10, t11 = m11;
#pragma unroll
        for (int bit = 0; bit < 8; ++bit) {
            if ((tid >> bit) & 1) {
                float n0, n1;
                n0 = fmaf(t00, vA0, t01 * vA1); n1 = fmaf(t10, vA0, t11 * vA1);
                vA0 = n0; vA1 = n1;
                n0 = fmaf(t00, vB0, t01 * vB1); n1 = fmaf(t10, vB0, t11 * vB1);
                vB0 = n0; vB1 = n1;
                if (bit < 6) {                  // lane bits == tid bits 0..5
                    n0 = fmaf(t00, vcA0, t01 * vcA1); n1 = fmaf(t10, vcA0, t11 * vcA1);
                    vcA0 = n0; vcA1 = n1;
                    n0 = fmaf(t00, vcB0, t01 * vcB1); n1 = fmaf(t10, vcB0, t11 * vcB1);
                    vcB0 = n0; vcB1 = n1;
                }
            }
            MATSQ(t00, t01, t10, t11);
        }
    }
    float v0 = vA0 + vcA0 + einA0;
    float v1 = vA1 + vcA1 + einA1;
    float u0 = vB0 + vcB0 + einB0;
    float u1 = vB1 + vcB1 + einB1;

    // ---- pass 2 tile A: DF-I from registers -> ldsA ----
    {
        float o2 = fmaf(xv[0], b0, v0);
        float vn0 = fmaf(na1, o2, fmaf(xv[0], b1, v1));
        float o1 = fmaf(xv[1], b0, vn0);
        ldsA[tid][0] = o2; ldsA[tid][1] = o1;
#pragma unroll
        for (int t = 2; t < LPT; ++t) {
            float acc = fmaf(b1, xv[t - 1], fmaf(b2, xv[t - 2], na2 * o2));
            float o   = fmaf(b0, xv[t], fmaf(na1, o1, acc));
            ldsA[tid][t] = o;
            o2 = o1; o1 = o;
        }
    }
    // ---- pass 2 tile B: DF-I from LDS rows, in-place overwrite ----
    {
        float xm2 = ldsB[tid][0], xm1 = ldsB[tid][1];
        float o2 = fmaf(xm2, b0, u0);
        float vn0 = fmaf(na1, o2, fmaf(xm2, b1, u1));
        float o1 = fmaf(xm1, b0, vn0);
        ldsB[tid][0] = o2; ldsB[tid][1] = o1;
#pragma unroll
        for (int t = 2; t < LPT; ++t) {
            float xt  = ldsB[tid][t];
            float acc = fmaf(b1, xm1, fmaf(b2, xm2, na2 * o2));
            float o   = fmaf(b0, xt, fmaf(na1, o1, acc));
            ldsB[tid][t] = o;
            xm2 = xm1; xm1 = xt;
            o2 = o1; o1 = o;
        }
    }
    __syncthreads();                                     // barrier #3

    // ---- coalesced NON-TEMPORAL stores, both tiles ----
    vfloat4* dstA = reinterpret_cast<vfloat4*>(out + base);
    vfloat4* dstB = dstA + TILE / 4;
#pragma unroll
    for (int it = 0; it < 8; ++it) {
        int idx = it * TPB + tid;
        int e = idx * 4, c = e >> 5, t = e & 31;
        vfloat4 v;
        v.x = ldsA[c][t];     v.y = ldsA[c][t + 1];
        v.z = ldsA[c][t + 2]; v.w = ldsA[c][t + 3];
        __builtin_nontemporal_store(v, &dstA[idx]);
    }
#pragma unroll
    for (int it = 0; it < 8; ++it) {
        int idx = it * TPB + tid;
        int e = idx * 4, c = e >> 5, t = e & 31;
        vfloat4 v;
        v.x = ldsB[c][t];     v.y = ldsB[c][t + 1];
        v.z = ldsB[c][t + 2]; v.w = ldsB[c][t + 3];
        __builtin_nontemporal_store(v, &dstB[idx]);
    }
}

extern "C" void kernel_launch(void* const* d_in, const int* in_sizes, int n_in,
                              void* d_out, int out_size, void* d_ws, size_t ws_size,
                              hipStream_t stream) {
    const float* x   = (const float*)d_in[0];
    const float* pb0 = (const float*)d_in[1];
    const float* pb1 = (const float*)d_in[2];
    const float* pb2 = (const float*)d_in[3];
    const float* pa1 = (const float*)d_in[4];
    const float* pa2 = (const float*)d_in[5];
    float* out = (float*)d_out;

    biquad_2tile<<<NB, TPB, 0, stream>>>(x, out, pb0, pb1, pb2, pa1, pa2);
}